// Round 4
// baseline (173.774 us; speedup 1.0000x reference)
//
#include <hip/hip_runtime.h>

// InformPooling, two-pass chunk-sum scheme.
//   value0 [8,16384,128] r=1.0 ; value1 [8,8192,128] r=0.5 ; value2 [8,4096,256] r=0.25
//   start/duration [8,512]; out [8,512,512] f32 (channels concat 128|128|256).
//
// Pass 1 (chunk_sum): stream v once, write sums of kC=8 consecutive rows into d_ws.
//   S0 flat [16384][128], S1 [8192][128], S2 [4096][256] -> 16.8 MB (LLC-hot).
//   R2 post-mortem: short waves (8 loads then die) capped at 3.3 TB/s regardless of
//   load width -> per-wave MLP limit. R3: 3584 long-lived waves, 4-8 chunk iterations
//   each, manual prefetch double-buffer so next chunk's loads issue before current
//   chunk's sum (s_waitcnt vmcnt(8), never 0 mid-loop).
// Pass 2 (gather): per (b,n,pool) wave; interior from S, <=7 edge rows from v.

constexpr int   kB   = 8;
constexpr int   kN   = 512;
constexpr float kEps = 1e-3f;
constexpr int   kC   = 8;  // chunk rows

// float offsets into ws
constexpr size_t S0_OFF = 0;                       // 16384*128
constexpr size_t S1_OFF = (size_t)16384 * 128;     // + 8192*128
constexpr size_t S2_OFF = S1_OFF + (size_t)8192 * 128;

static __device__ __forceinline__ float4 f4add(float4 a, float4 b) {
    a.x += b.x; a.y += b.y; a.z += b.z; a.w += b.w; return a;
}

// 128-ch pools: half-wave (32 lanes x float4) per chunk, ITERS chunk-pairs per wave.
template<int W, int ITERS>
static __device__ __forceinline__ void chunks128(
    const float4* __restrict__ v, float4* __restrict__ S, int wloc, int lane)
{
    const int half = lane >> 5;
    const int q    = lane & 31;
    int C = wloc * 2 + half;          // flat chunk id; advances by 2*W
    constexpr int step = 2 * W;

    float4 buf[8];
    {
        const float4* p = v + (size_t)C * (kC * 32) + q;
#pragma unroll
        for (int i = 0; i < kC; i++) buf[i] = p[(size_t)i * 32];
    }
#pragma unroll
    for (int it = 0; it < ITERS; it++) {
        float4 nbuf[8];
        if (it < ITERS - 1) {
            const float4* np = v + (size_t)(C + step) * (kC * 32) + q;
#pragma unroll
            for (int i = 0; i < kC; i++) nbuf[i] = np[(size_t)i * 32];
        }
        float4 s01 = f4add(buf[0], buf[1]), s23 = f4add(buf[2], buf[3]);
        float4 s45 = f4add(buf[4], buf[5]), s67 = f4add(buf[6], buf[7]);
        S[(size_t)C * 32 + q] = f4add(f4add(s01, s23), f4add(s45, s67));
        if (it < ITERS - 1) {
#pragma unroll
            for (int i = 0; i < kC; i++) buf[i] = nbuf[i];
        }
        C += step;
    }
}

// 256-ch pool: full wave (64 lanes x float4) per row, ITERS chunks per wave.
template<int W, int ITERS>
static __device__ __forceinline__ void chunks256(
    const float4* __restrict__ v, float4* __restrict__ S, int wloc, int lane)
{
    int C = wloc;                     // flat chunk id; advances by W

    float4 buf[8];
    {
        const float4* p = v + (size_t)C * (kC * 64) + lane;
#pragma unroll
        for (int i = 0; i < kC; i++) buf[i] = p[(size_t)i * 64];
    }
#pragma unroll
    for (int it = 0; it < ITERS; it++) {
        float4 nbuf[8];
        if (it < ITERS - 1) {
            const float4* np = v + (size_t)(C + W) * (kC * 64) + lane;
#pragma unroll
            for (int i = 0; i < kC; i++) nbuf[i] = np[(size_t)i * 64];
        }
        float4 s01 = f4add(buf[0], buf[1]), s23 = f4add(buf[2], buf[3]);
        float4 s45 = f4add(buf[4], buf[5]), s67 = f4add(buf[6], buf[7]);
        S[(size_t)C * 64 + lane] = f4add(f4add(s01, s23), f4add(s45, s67));
        if (it < ITERS - 1) {
#pragma unroll
            for (int i = 0; i < kC; i++) buf[i] = nbuf[i];
        }
        C += W;
    }
}

__global__ __launch_bounds__(256) void chunk_sum_kernel(
    const float* __restrict__ v0, const float* __restrict__ v1,
    const float* __restrict__ v2, float* __restrict__ ws)
{
    const int w    = (blockIdx.x * 256 + threadIdx.x) >> 6;  // [0, 3584)
    const int lane = threadIdx.x & 63;

    if (w < 2048) {            // pool0: 16384 chunks = 2048 waves x 4 iters x 2
        chunks128<2048, 4>((const float4*)v0, (float4*)(ws + S0_OFF), w, lane);
    } else if (w < 3072) {     // pool1: 8192 chunks = 1024 waves x 4 iters x 2
        chunks128<1024, 4>((const float4*)v1, (float4*)(ws + S1_OFF), w - 2048, lane);
    } else {                   // pool2: 4096 chunks = 512 waves x 8 iters
        chunks256<512, 8>((const float4*)v2, (float4*)(ws + S2_OFF), w - 3072, lane);
    }
}

__global__ __launch_bounds__(256) void gather_kernel(
    const float* __restrict__ v0, const float* __restrict__ v1,
    const float* __restrict__ v2, const float* __restrict__ start,
    const float* __restrict__ dur, const float* __restrict__ ws,
    float* __restrict__ out)
{
    const int wave = threadIdx.x >> 6;
    const int lane = threadIdx.x & 63;
    const int half = lane >> 5;
    const int q    = lane & 31;
    const int bn   = blockIdx.x * 4 + wave;   // [0, 4096)
    const int b    = bn >> 9;
    const int pool = blockIdx.y;

    const float st = start[bn];
    const float du = dur[bn];
    float* outbase = out + (size_t)bn * 512;

    if (pool < 2) {
        const float* v  = (pool == 0) ? v0 : v1;
        const float* S  = ws + ((pool == 0) ? S0_OFF : S1_OFF);
        const int    T  = (pool == 0) ? 16384 : 8192;
        const int    NC = T / kC;
        const float  r  = (pool == 0) ? 1.0f : 0.5f;
        const int s = min((int)floorf(st * r), T - 1);
        const int e = min((int)ceilf((st + du + kEps) * r), T - 1);
        const int cnt = e - s;

        float4 a = make_float4(0, 0, 0, 0);
        if (cnt > 0) {
            const float4* vp = (const float4*)(v + (size_t)b * T * 128) + q;   // row t: vp[t*32]
            const int cs = (s + kC - 1) >> 3;
            const int ce = e >> 3;
            if (ce > cs) {
                const float4* Sp = (const float4*)(S + (size_t)b * NC * 128) + q; // chunk c: Sp[c*32]
                for (int c = cs + half; c < ce; c += 2)
                    a = f4add(a, Sp[(size_t)c * 32]);
                for (int t = s + half; t < cs * kC; t += 2)      // front edge (<=7 rows)
                    a = f4add(a, vp[(size_t)t * 32]);
                for (int t = ce * kC + half; t < e; t += 2)      // back edge (<=7 rows)
                    a = f4add(a, vp[(size_t)t * 32]);
            } else {
                for (int t = s + half; t < e; t += 2)            // short segment
                    a = f4add(a, vp[(size_t)t * 32]);
            }
        }
        a.x += __shfl_xor(a.x, 32);
        a.y += __shfl_xor(a.y, 32);
        a.z += __shfl_xor(a.z, 32);
        a.w += __shfl_xor(a.w, 32);
        float4 res = make_float4(0, 0, 0, 0);
        if (cnt > 0) {
            const float c = (float)cnt;
            res.x = a.x / c; res.y = a.y / c; res.z = a.z / c; res.w = a.w / c;
        }
        if (lane < 32)
            ((float4*)(outbase + (pool == 0 ? 0 : 128)))[q] = res;
    } else {
        const int   T  = 4096;
        const int   NC = T / kC;
        const float r  = 0.25f;
        const int s = min((int)floorf(st * r), T - 1);
        const int e = min((int)ceilf((st + du + kEps) * r), T - 1);
        const int cnt = e - s;

        float4 a0 = make_float4(0, 0, 0, 0), a1 = make_float4(0, 0, 0, 0);
        if (cnt > 0) {
            const float4* vp = (const float4*)(v2 + (size_t)b * T * 256) + lane;  // row t: vp[t*64]
            const int cs = (s + kC - 1) >> 3;
            const int ce = e >> 3;
            if (ce > cs) {
                const float4* Sp = (const float4*)(ws + S2_OFF + (size_t)b * NC * 256) + lane;
                int c = cs;
                for (; c + 2 <= ce; c += 2) {
                    a0 = f4add(a0, Sp[(size_t)c * 64]);
                    a1 = f4add(a1, Sp[(size_t)(c + 1) * 64]);
                }
                if (c < ce) a0 = f4add(a0, Sp[(size_t)c * 64]);
                for (int t = s; t < cs * kC; t++) a0 = f4add(a0, vp[(size_t)t * 64]);
                for (int t = ce * kC; t < e; t++) a1 = f4add(a1, vp[(size_t)t * 64]);
            } else {
                for (int t = s; t < e; t++) a0 = f4add(a0, vp[(size_t)t * 64]);
            }
        }
        float4 res = make_float4(0, 0, 0, 0);
        if (cnt > 0) {
            const float c = (float)cnt;
            res.x = (a0.x + a1.x) / c;
            res.y = (a0.y + a1.y) / c;
            res.z = (a0.z + a1.z) / c;
            res.w = (a0.w + a1.w) / c;
        }
        ((float4*)(outbase + 256))[lane] = res;
    }
}

extern "C" void kernel_launch(void* const* d_in, const int* in_sizes, int n_in,
                              void* d_out, int out_size, void* d_ws, size_t ws_size,
                              hipStream_t stream) {
    const float* v0    = (const float*)d_in[0];
    const float* v1    = (const float*)d_in[1];
    const float* v2    = (const float*)d_in[2];
    const float* start = (const float*)d_in[3];
    const float* dur   = (const float*)d_in[4];
    float*       out   = (float*)d_out;
    float*       ws    = (float*)d_ws;

    // Pass 1: 3584 long-lived waves (2048 pool0 + 1024 pool1 + 512 pool2), 4 waves/block
    chunk_sum_kernel<<<dim3(3584 / 4), 256, 0, stream>>>(v0, v1, v2, ws);
    // Pass 2: one wave per (bn, pool)
    gather_kernel<<<dim3(kB * kN / 4, 3), 256, 0, stream>>>(v0, v1, v2, start, dur, ws, out);
}